// Round 1
// baseline (992.052 us; speedup 1.0000x reference)
//
#include <hip/hip_runtime.h>

#define N_NODES 100000
#define N_EDGES 1600000
#define STRN 264        // node LDS row stride in ushorts (256 + 8 pad)
#define NBLK_SCAN 391   // ceil(100000/256)

typedef __attribute__((ext_vector_type(4))) float floatx4;
typedef __attribute__((ext_vector_type(8))) __bf16 bf16x8;
typedef __attribute__((ext_vector_type(8))) unsigned short ushort8;
typedef __attribute__((ext_vector_type(4))) unsigned short ushort4v;

// ---- ws layout (bytes) ----
#define WS_AGGR   0ull                        // 51,200,000  fp32 [N][128]
#define WS_COUNTS 51200000ull                 // 400,384     int[100096]
#define WS_OFFS   51600384ull                 // 400,384
#define WS_PART   52000768ull                 // 2,048       int[512]
#define WS_DSTS   52002816ull                 // 6,400,000   int[E] (dst-sorted)
#define WS_ATTRS  58402816ull                 // 32,000,000  fp32 [E][5] (dst-sorted)
#define WS_W2     90402816ull                 // Wm2 bf16 [128][128]
#define WS_W3     (WS_W2 + 32768ull)
#define WS_WU1    (WS_W3 + 32768ull)          // Wu1 bf16 padded [224][256]
#define WS_WU2    (WS_WU1 + 114688ull)        // Wu2 bf16 padded [192][224]
#define WS_WU3    (WS_WU2 + 86016ull)         // Wu3 bf16 padded [128][192]

// compiler cast lowers to native RNE cvt (faster than 4-op manual RNE)
__device__ __forceinline__ unsigned short tobf(float f) {
  return __builtin_bit_cast(unsigned short, (__bf16)f);
}

__device__ __forceinline__ float leaky(float v) { return fmaxf(v, 0.01f * v); }

// XOR-swizzled ushort index into a [128 rows][128 ch] bf16 LDS tile.
__device__ __forceinline__ int swz(int row, int ch) {
  return row * 128 + (ch ^ ((row & 7) << 3));
}

// ---------------- weight prep: fp32 -> bf16 (+ zero padding) ----------------
__global__ void prep_kernel(const float* __restrict__ Wm2, const float* __restrict__ Wm3,
                            const float* __restrict__ Wu1, const float* __restrict__ Wu2,
                            const float* __restrict__ Wu3,
                            unsigned short* __restrict__ o2, unsigned short* __restrict__ o3,
                            unsigned short* __restrict__ o1p, unsigned short* __restrict__ o2p,
                            unsigned short* __restrict__ o3p) {
  int i = blockIdx.x * 256 + threadIdx.x;
  if (i < 16384) {
    o2[i] = tobf(Wm2[i]);
  } else if (i < 32768) {
    int j = i - 16384; o3[j] = tobf(Wm3[j]);
  } else if (i < 32768 + 57344) {            // Wu1 pad [214][256] -> [224][256]
    int j = i - 32768; int n = j >> 8, k = j & 255;
    o1p[j] = (n < 214) ? tobf(Wu1[n * 256 + k]) : (unsigned short)0;
  } else if (i < 90112 + 43008) {            // Wu2 pad [172][214] -> [192][224]
    int j = i - 90112; int n = j / 224, k = j - n * 224;
    o2p[j] = (n < 172 && k < 214) ? tobf(Wu2[n * 214 + k]) : (unsigned short)0;
  } else if (i < 133120 + 24576) {           // Wu3 pad [128][172] -> [128][192]
    int j = i - 133120; int n = j / 192, k = j - n * 192;
    o3p[j] = (k < 172) ? tobf(Wu3[n * 172 + k]) : (unsigned short)0;
  }
}

// ---------------- counting sort of edges by dst ----------------
__global__ void hist_kernel(const int* __restrict__ dst, int* __restrict__ counts) {
  int e = blockIdx.x * 256 + threadIdx.x;
  if (e < N_EDGES) atomicAdd(&counts[dst[e]], 1);
}

__global__ void scanA_kernel(const int* __restrict__ counts, int* __restrict__ offs,
                             int* __restrict__ partials) {
  __shared__ int tmp[256];
  const int t = threadIdx.x;
  const int i = blockIdx.x * 256 + t;
  int v = (i < N_NODES) ? counts[i] : 0;
  tmp[t] = v;
  __syncthreads();
  for (int off = 1; off < 256; off <<= 1) {
    int a = (t >= off) ? tmp[t - off] : 0;
    __syncthreads();
    tmp[t] += a;
    __syncthreads();
  }
  if (i < N_NODES) offs[i] = tmp[t] - v;  // exclusive
  if (t == 255) partials[blockIdx.x] = tmp[255];
}

__global__ void scanB_kernel(int* __restrict__ partials) {
  __shared__ int tmp[512];
  const int t = threadIdx.x;
  int v = (t < NBLK_SCAN) ? partials[t] : 0;
  tmp[t] = v;
  __syncthreads();
  for (int off = 1; off < 512; off <<= 1) {
    int a = (t >= off) ? tmp[t - off] : 0;
    __syncthreads();
    tmp[t] += a;
    __syncthreads();
  }
  if (t < NBLK_SCAN) partials[t] = tmp[t] - v;  // exclusive
}

__global__ void scanC_kernel(int* __restrict__ offs, const int* __restrict__ partials) {
  int i = blockIdx.x * 256 + threadIdx.x;
  if (i < N_NODES) offs[i] += partials[blockIdx.x];
}

// scatter: reorder the edge PAYLOAD (attr rows + dst), not just indices.
// Reads coalesced; scattered stores are fire-and-forget at high occupancy.
__global__ void scatter_kernel(const int* __restrict__ dst, int* __restrict__ offs,
                               const float* __restrict__ attr,
                               float* __restrict__ attrS, int* __restrict__ dsts) {
  int e = blockIdx.x * 256 + threadIdx.x;
  if (e < N_EDGES) {
    int d = dst[e];
    int p = atomicAdd(&offs[d], 1);
    dsts[p] = d;
    const float* a = attr + (size_t)e * 5;
    float a0 = a[0], a1 = a[1], a2 = a[2], a3 = a[3], a4 = a[4];
    float* o = attrS + (size_t)p * 5;
    o[0] = a0; o[1] = a1; o[2] = a2; o[3] = a3; o[4] = a4;
  }
}

// ---------------- edge kernel: MLP(attrS) on dst-sorted edges + segmented scatter ----
// LDS 39.5KB -> 4 blocks/CU. All post-stage phases are wave-local (own 32 rows):
// only 2 barriers per block. B operands streamed from global (L1-hot 32KB tiles).
__global__ __launch_bounds__(256, 4) void edge_kernel(
    const float* __restrict__ attrS, const int* __restrict__ dsts,
    const float* __restrict__ Wm1, const float* __restrict__ bm1,
    const unsigned short* __restrict__ W2bf, const float* __restrict__ bm2,
    const unsigned short* __restrict__ W3bf, const float* __restrict__ bm3,
    float* __restrict__ aggr) {
  __shared__ __align__(16) char smem[40448];
  unsigned short* sH = (unsigned short*)(void*)smem;   // [0,32768): h tile bf16, swizzled
  float* sMsg = (float*)(void*)smem;                   // [0,33792): 128 rows x 66 fp32 (post-MFMA)
  float* sAttr8 = (float*)(void*)(smem + 33792);       // [33792,37888): 128x8 attr rows
  float* sWm1F = (float*)(void*)(smem + 37888);        // [37888,40448): 640 floats

  const int t = threadIdx.x;
  const int wave = t >> 6, lane = t & 63;
  const int col = lane & 15, q = lane >> 4;
  const int eb = wave * 32;
  const long blockEdge = (long)blockIdx.x * 128;

  // ---- stage: Wm1 + this block's dst-sorted attr slab (fully coalesced) ----
  for (int i = t; i < 640; i += 256) {
    sWm1F[i] = Wm1[i];
    float v = attrS[blockEdge * 5 + i];
    int e = i / 5, j = i - e * 5;
    sAttr8[e * 8 + j] = v;
  }
  const int dAll = dsts[blockEdge + eb + (lane & 31)];  // this wave's quarter dsts
  __syncthreads();

  // ---- layer 1 (fp32 vector): lane -> channels {lane, lane+64}, wave-own 32 rows ----
  {
    const int c = lane;
    const float* wa = sWm1F + c * 5;
    const float* wb = sWm1F + (c + 64) * 5;
    float wa0 = wa[0], wa1 = wa[1], wa2 = wa[2], wa3 = wa[3], wa4 = wa[4];
    float wb0 = wb[0], wb1 = wb[1], wb2 = wb[2], wb3 = wb[3], wb4 = wb[4];
    float ba = bm1[c], bb = bm1[c + 64];
#pragma unroll 4
    for (int e = 0; e < 32; e++) {
      const float* ar = sAttr8 + (eb + e) * 8;
      float4 a = *(const float4*)ar;
      float a4 = ar[4];
      float ha = fmaf(a.x, wa0, fmaf(a.y, wa1, fmaf(a.z, wa2, fmaf(a.w, wa3, fmaf(a4, wa4, ba)))));
      float hb = fmaf(a.x, wb0, fmaf(a.y, wb1, fmaf(a.z, wb2, fmaf(a.w, wb3, fmaf(a4, wb4, bb)))));
      sH[swz(eb + e, c)] = tobf(leaky(ha));
      sH[swz(eb + e, c + 64)] = tobf(leaky(hb));
    }
  }
  // wave-local cross-lane RAW on sH: DS pipe is in-order per wave; drain to be safe
  asm volatile("s_waitcnt lgkmcnt(0)" ::: "memory");

  // ---- layer 2: MFMA, B streamed from global, epilogue back to sH (wave-own rows) ----
  {
    floatx4 acc2[2][8];
#pragma unroll
    for (int i = 0; i < 2; i++)
#pragma unroll
      for (int j = 0; j < 8; j++) acc2[i][j] = (floatx4){0.f, 0.f, 0.f, 0.f};
#pragma unroll
    for (int ks = 0; ks < 4; ks++) {
      const int kk = ks * 32 + q * 8;
      bf16x8 a0 = *(const bf16x8*)(const void*)&sH[swz(eb + col, kk)];
      bf16x8 a1 = *(const bf16x8*)(const void*)&sH[swz(eb + 16 + col, kk)];
#pragma unroll
      for (int nt = 0; nt < 8; nt++) {
        bf16x8 b = *(const bf16x8*)(const void*)&W2bf[(nt * 16 + col) * 128 + kk];
        acc2[0][nt] = __builtin_amdgcn_mfma_f32_16x16x32_bf16(a0, b, acc2[0][nt], 0, 0, 0);
        acc2[1][nt] = __builtin_amdgcn_mfma_f32_16x16x32_bf16(a1, b, acc2[1][nt], 0, 0, 0);
      }
    }
#pragma unroll
    for (int nt = 0; nt < 8; nt++) {
      const int n = nt * 16 + col;
      const float bv = bm2[n];
#pragma unroll
      for (int i = 0; i < 2; i++)
#pragma unroll
        for (int r = 0; r < 4; r++)
          sH[swz(eb + i * 16 + q * 4 + r, n)] = tobf(leaky(acc2[i][nt][r] + bv));
    }
  }
  asm volatile("s_waitcnt lgkmcnt(0)" ::: "memory");

  // ---- layer 3: MFMA (B from global) ----
  floatx4 acc[2][8];
#pragma unroll
  for (int i = 0; i < 2; i++)
#pragma unroll
    for (int j = 0; j < 8; j++) acc[i][j] = (floatx4){0.f, 0.f, 0.f, 0.f};
#pragma unroll
  for (int ks = 0; ks < 4; ks++) {
    const int kk = ks * 32 + q * 8;
    bf16x8 a0 = *(const bf16x8*)(const void*)&sH[swz(eb + col, kk)];
    bf16x8 a1 = *(const bf16x8*)(const void*)&sH[swz(eb + 16 + col, kk)];
#pragma unroll
    for (int nt = 0; nt < 8; nt++) {
      bf16x8 b = *(const bf16x8*)(const void*)&W3bf[(nt * 16 + col) * 128 + kk];
      acc[0][nt] = __builtin_amdgcn_mfma_f32_16x16x32_bf16(a0, b, acc[0][nt], 0, 0, 0);
      acc[1][nt] = __builtin_amdgcn_mfma_f32_16x16x32_bf16(a1, b, acc[1][nt], 0, 0, 0);
    }
  }
  __syncthreads();  // all waves done reading sH; smem becomes sMsg (overlay)

  // ---- two channel-halves: epilogue fp32 -> sMsg, then segmented walk + atomics ----
  // sMsg rows are wave-disjoint (stride 66 floats) -> no further barriers needed.
#pragma unroll
  for (int h = 0; h < 2; h++) {
#pragma unroll
    for (int k = 0; k < 4; k++) {
      const int nt = h * 4 + k;
      const int n = nt * 16 + col;
      const float bv = bm3[n];
      const int cl = n - h * 64;
#pragma unroll
      for (int i = 0; i < 2; i++)
#pragma unroll
        for (int r = 0; r < 4; r++)
          sMsg[(eb + i * 16 + q * 4 + r) * 66 + cl] = acc[i][nt][r] + bv;
    }
    asm volatile("s_waitcnt lgkmcnt(0)" ::: "memory");  // wave-local writes visible

    const int cc = lane + h * 64;  // channel
    float accv = 0.f;
    int dprev = __shfl(dAll, 0);
#pragma unroll
    for (int e = 0; e < 32; e++) {
      int d = __shfl(dAll, e);  // wave-uniform -> scalar branch
      float v = sMsg[(eb + e) * 66 + lane];
      if (d != dprev) {
        atomicAdd(&aggr[(size_t)dprev * 128 + cc], accv);
        accv = 0.f;
        dprev = d;
      }
      accv += v;
    }
    atomicAdd(&aggr[(size_t)dprev * 128 + cc], accv);
  }
}

// ---------------- node layer (MFMA) ----------------
template <int NT, int KST, bool FINAL>
__device__ __forceinline__ void layer_node(unsigned short* __restrict__ sX,
                                           const unsigned short* __restrict__ W,
                                           const float* __restrict__ bias, int biasLim,
                                           int wave, int lane, int nodeGBase,
                                           float* __restrict__ out) {
  const int col = lane & 15, q = lane >> 4;
  floatx4 acc[NT];
#pragma unroll
  for (int i = 0; i < NT; i++) acc[i] = (floatx4){0.f, 0.f, 0.f, 0.f};
  const int rowA = wave * 16 + col;
#pragma unroll
  for (int ks = 0; ks < KST; ks++) {
    const int kk = ks * 32 + q * 8;
    bf16x8 a = *(const bf16x8*)(const void*)&sX[rowA * STRN + kk];
#pragma unroll
    for (int nt = 0; nt < NT; nt++) {
      bf16x8 b = *(const bf16x8*)(const void*)&W[(nt * 16 + col) * (KST * 32) + kk];
      acc[nt] = __builtin_amdgcn_mfma_f32_16x16x32_bf16(a, b, acc[nt], 0, 0, 0);
    }
  }
#pragma unroll
  for (int nt = 0; nt < NT; nt++) {
    const int n = nt * 16 + col;
    const float bv = (n < biasLim) ? bias[n] : 0.f;
#pragma unroll
    for (int r = 0; r < 4; r++) {
      const int row = wave * 16 + q * 4 + r;
      float v = acc[nt][r] + bv;
      if (!FINAL) {
        sX[row * STRN + n] = tobf(leaky(v));
      } else {
        const long ng = (long)nodeGBase + row;
        if (ng < N_NODES) out[ng * 128 + n] = v;
      }
    }
  }
}

// ---------------- node kernel: LN(concat) + MLP ----------------
__global__ __launch_bounds__(256, 2) void node_kernel(
    const float* __restrict__ x, const float* __restrict__ aggr,
    const float* __restrict__ lng, const float* __restrict__ lnb,
    const unsigned short* __restrict__ Wu1p, const float* __restrict__ bu1,
    const unsigned short* __restrict__ Wu2p, const float* __restrict__ bu2,
    const unsigned short* __restrict__ Wu3p, const float* __restrict__ bu3,
    float* __restrict__ out) {
  __shared__ unsigned short sX[64 * STRN];  // [node][c] bf16, padded stride
  __shared__ float sG[256], sB[256];
  const int t = threadIdx.x;
  const int wave = t >> 6, lane = t & 63;
  sG[t] = lng[t];
  sB[t] = lnb[t];

  // LayerNorm over cat=[x,aggr] (fp32). 4 threads per node.
  const int nl = t >> 2;
  const int part = t & 3;
  const long nodeG = (long)blockIdx.x * 64 + nl;
  const bool valid = nodeG < N_NODES;
  const float* src = (part < 2) ? (x + nodeG * 128 + part * 64)
                                : (aggr + nodeG * 128 + (part - 2) * 64);
  float s = 0.f, ss = 0.f;
  if (valid) {
#pragma unroll
    for (int i = 0; i < 16; i++) {
      float4 a = *(const float4*)(src + i * 4);
      s += a.x + a.y + a.z + a.w;
      ss += a.x * a.x + a.y * a.y + a.z * a.z + a.w * a.w;
    }
  }
  s += __shfl_xor(s, 1); s += __shfl_xor(s, 2);
  ss += __shfl_xor(ss, 1); ss += __shfl_xor(ss, 2);
  const float mean = s * (1.f / 256.f);
  const float var = ss * (1.f / 256.f) - mean * mean;
  const float rstd = rsqrtf(var + 1e-5f);
  __syncthreads();  // sG/sB visible
  const int cb = part * 64;
#pragma unroll
  for (int i = 0; i < 16; i++) {
    float4 a = valid ? *(const float4*)(src + i * 4) : make_float4(0.f, 0.f, 0.f, 0.f);
    int c = cb + i * 4;
    ushort4v p;
    p[0] = tobf((a.x - mean) * rstd * sG[c + 0] + sB[c + 0]);
    p[1] = tobf((a.y - mean) * rstd * sG[c + 1] + sB[c + 1]);
    p[2] = tobf((a.z - mean) * rstd * sG[c + 2] + sB[c + 2]);
    p[3] = tobf((a.w - mean) * rstd * sG[c + 3] + sB[c + 3]);
    *(ushort4v*)(void*)&sX[nl * STRN + c] = p;
  }
  __syncthreads();

  const int nodeGBase = blockIdx.x * 64;
  layer_node<14, 8, false>(sX, Wu1p, bu1, 214, wave, lane, nodeGBase, nullptr);
  __syncthreads();
  layer_node<12, 7, false>(sX, Wu2p, bu2, 172, wave, lane, nodeGBase, nullptr);
  __syncthreads();
  layer_node<8, 6, true>(sX, Wu3p, bu3, 128, wave, lane, nodeGBase, out);
}

// ---------------- launch ----------------
extern "C" void kernel_launch(void* const* d_in, const int* in_sizes, int n_in,
                              void* d_out, int out_size, void* d_ws, size_t ws_size,
                              hipStream_t stream) {
  const float* x    = (const float*)d_in[0];
  const int*   eidx = (const int*)d_in[1];
  const float* attr = (const float*)d_in[2];
  const float* Wm1  = (const float*)d_in[3];
  const float* bm1  = (const float*)d_in[4];
  const float* Wm2  = (const float*)d_in[5];
  const float* bm2  = (const float*)d_in[6];
  const float* Wm3  = (const float*)d_in[7];
  const float* bm3  = (const float*)d_in[8];
  const float* lng  = (const float*)d_in[9];
  const float* lnb  = (const float*)d_in[10];
  const float* Wu1  = (const float*)d_in[11];
  const float* bu1  = (const float*)d_in[12];
  const float* Wu2  = (const float*)d_in[13];
  const float* bu2  = (const float*)d_in[14];
  const float* Wu3  = (const float*)d_in[15];
  const float* bu3  = (const float*)d_in[16];
  float* out = (float*)d_out;

  char* ws = (char*)d_ws;
  float* aggr  = (float*)(ws + WS_AGGR);
  int* counts  = (int*)(ws + WS_COUNTS);
  int* offs    = (int*)(ws + WS_OFFS);
  int* parts   = (int*)(ws + WS_PART);
  int* dsts    = (int*)(ws + WS_DSTS);
  float* attrS = (float*)(ws + WS_ATTRS);
  unsigned short* W2bf = (unsigned short*)(ws + WS_W2);
  unsigned short* W3bf = (unsigned short*)(ws + WS_W3);
  unsigned short* Wu1p = (unsigned short*)(ws + WS_WU1);
  unsigned short* Wu2p = (unsigned short*)(ws + WS_WU2);
  unsigned short* Wu3p = (unsigned short*)(ws + WS_WU3);

  const int* dst = eidx + N_EDGES;  // edge_index[1]

  // counting sort of edges by dst (payload reorder: attrS + dsts)
  hipMemsetAsync(counts, 0, 400384, stream);
  hist_kernel<<<6250, 256, 0, stream>>>(dst, counts);
  scanA_kernel<<<NBLK_SCAN, 256, 0, stream>>>(counts, offs, parts);
  scanB_kernel<<<1, 512, 0, stream>>>(parts);
  scanC_kernel<<<NBLK_SCAN, 256, 0, stream>>>(offs, parts);
  scatter_kernel<<<6250, 256, 0, stream>>>(dst, offs, attr, attrS, dsts);

  hipMemsetAsync(aggr, 0, (size_t)N_NODES * 128 * sizeof(float), stream);
  prep_kernel<<<616, 256, 0, stream>>>(Wm2, Wm3, Wu1, Wu2, Wu3, W2bf, W3bf, Wu1p, Wu2p, Wu3p);

  edge_kernel<<<N_EDGES / 128, 256, 0, stream>>>(attrS, dsts, Wm1, bm1, W2bf, bm2, W3bf,
                                                 bm3, aggr);
  node_kernel<<<(N_NODES + 63) / 64, 256, 0, stream>>>(x, aggr, lng, lnb, Wu1p, bu1, Wu2p, bu2,
                                                       Wu3p, bu3, out);
}

// Round 2
// 816.231 us; speedup vs baseline: 1.2154x; 1.2154x over previous
//
#include <hip/hip_runtime.h>

#define N_NODES 100000
#define N_EDGES 1600000
#define STRN 264        // node LDS row stride in ushorts (256 + 8 pad)
#define NBLK_SCAN 391   // ceil(100000/256)

typedef __attribute__((ext_vector_type(4))) float floatx4;
typedef __attribute__((ext_vector_type(8))) __bf16 bf16x8;
typedef __attribute__((ext_vector_type(8))) unsigned short ushort8;
typedef __attribute__((ext_vector_type(4))) unsigned short ushort4v;

// ---- ws layout (bytes) ----
#define WS_AGGR   0ull                        // 51,200,000  fp32 [N][128]
#define WS_COUNTS 51200000ull                 // 400,384     int[100096]
#define WS_OFFS   51600384ull                 // 400,384
#define WS_PART   52000768ull                 // 2,048       int[512]
#define WS_DSTS   52002816ull                 // 6,400,000   int[E] (dst-sorted)
#define WS_ATTRS  58402816ull                 // 32,000,000  fp32 [E][5] (dst-sorted)
#define WS_W2     90402816ull                 // Wm2 bf16 [128][128]
#define WS_W3     (WS_W2 + 32768ull)
#define WS_WU1    (WS_W3 + 32768ull)          // Wu1 bf16 padded [224][256]
#define WS_WU2    (WS_WU1 + 114688ull)        // Wu2 bf16 padded [192][224]
#define WS_WU3    (WS_WU2 + 86016ull)         // Wu3 bf16 padded [128][192]

__device__ __forceinline__ unsigned short tobf(float f) {
  return __builtin_bit_cast(unsigned short, (__bf16)f);
}

__device__ __forceinline__ float leaky(float v) { return fmaxf(v, 0.01f * v); }

// XOR-swizzled ushort index into a [128 rows][128 ch] bf16 LDS tile.
__device__ __forceinline__ int swz(int row, int ch) {
  return row * 128 + (ch ^ ((row & 7) << 3));
}

// fp32 msg slab index: [128 edges][16 ch], XOR keeps both write & walk 2-way-free.
__device__ __forceinline__ int msw(int e, int ch) {
  return e * 16 + (ch ^ (((e >> 1) & 3) << 2));
}

// ---------------- weight prep: fp32 -> bf16 (+ zero padding) ----------------
__global__ void prep_kernel(const float* __restrict__ Wm2, const float* __restrict__ Wm3,
                            const float* __restrict__ Wu1, const float* __restrict__ Wu2,
                            const float* __restrict__ Wu3,
                            unsigned short* __restrict__ o2, unsigned short* __restrict__ o3,
                            unsigned short* __restrict__ o1p, unsigned short* __restrict__ o2p,
                            unsigned short* __restrict__ o3p) {
  int i = blockIdx.x * 256 + threadIdx.x;
  if (i < 16384) {
    o2[i] = tobf(Wm2[i]);
  } else if (i < 32768) {
    int j = i - 16384; o3[j] = tobf(Wm3[j]);
  } else if (i < 32768 + 57344) {            // Wu1 pad [214][256] -> [224][256]
    int j = i - 32768; int n = j >> 8, k = j & 255;
    o1p[j] = (n < 214) ? tobf(Wu1[n * 256 + k]) : (unsigned short)0;
  } else if (i < 90112 + 43008) {            // Wu2 pad [172][214] -> [192][224]
    int j = i - 90112; int n = j / 224, k = j - n * 224;
    o2p[j] = (n < 172 && k < 214) ? tobf(Wu2[n * 214 + k]) : (unsigned short)0;
  } else if (i < 133120 + 24576) {           // Wu3 pad [128][172] -> [128][192]
    int j = i - 133120; int n = j / 192, k = j - n * 192;
    o3p[j] = (k < 172) ? tobf(Wu3[n * 172 + k]) : (unsigned short)0;
  }
}

// ---------------- counting sort of edges by dst ----------------
__global__ void hist_kernel(const int* __restrict__ dst, int* __restrict__ counts) {
  int e = blockIdx.x * 256 + threadIdx.x;
  if (e < N_EDGES) atomicAdd(&counts[dst[e]], 1);
}

__global__ void scanA_kernel(const int* __restrict__ counts, int* __restrict__ offs,
                             int* __restrict__ partials) {
  __shared__ int tmp[256];
  const int t = threadIdx.x;
  const int i = blockIdx.x * 256 + t;
  int v = (i < N_NODES) ? counts[i] : 0;
  tmp[t] = v;
  __syncthreads();
  for (int off = 1; off < 256; off <<= 1) {
    int a = (t >= off) ? tmp[t - off] : 0;
    __syncthreads();
    tmp[t] += a;
    __syncthreads();
  }
  if (i < N_NODES) offs[i] = tmp[t] - v;  // exclusive
  if (t == 255) partials[blockIdx.x] = tmp[255];
}

__global__ void scanB_kernel(int* __restrict__ partials) {
  __shared__ int tmp[512];
  const int t = threadIdx.x;
  int v = (t < NBLK_SCAN) ? partials[t] : 0;
  tmp[t] = v;
  __syncthreads();
  for (int off = 1; off < 512; off <<= 1) {
    int a = (t >= off) ? tmp[t - off] : 0;
    __syncthreads();
    tmp[t] += a;
    __syncthreads();
  }
  if (t < NBLK_SCAN) partials[t] = tmp[t] - v;  // exclusive
}

__global__ void scanC_kernel(int* __restrict__ offs, const int* __restrict__ partials) {
  int i = blockIdx.x * 256 + threadIdx.x;
  if (i < N_NODES) offs[i] += partials[blockIdx.x];
}

// scatter: reorder the edge PAYLOAD (attr rows + dst) into dst-sorted order.
__global__ void scatter_kernel(const int* __restrict__ dst, int* __restrict__ offs,
                               const float* __restrict__ attr,
                               float* __restrict__ attrS, int* __restrict__ dsts) {
  int e = blockIdx.x * 256 + threadIdx.x;
  if (e < N_EDGES) {
    int d = dst[e];
    int p = atomicAdd(&offs[d], 1);
    dsts[p] = d;
    const float* a = attr + (size_t)e * 5;
    float a0 = a[0], a1 = a[1], a2 = a[2], a3 = a[3], a4 = a[4];
    float* o = attrS + (size_t)p * 5;
    o[0] = a0; o[1] = a1; o[2] = a2; o[3] = a3; o[4] = a4;
  }
}

// ---------------- edge kernel ----------------
// Swapped-operand MFMA: A = weight rows (wave owns 32 output channels, 8 frags
// prefetched into 32 VGPRs -> no latency chain), B = h tile from swizzled LDS.
// LDS 39.4KB -> 4 blocks/CU. Segment walk per wave over its 32 channels from a
// wave-private fp32 slab.
__global__ __launch_bounds__(256, 4) void edge_kernel(
    const float* __restrict__ attrS, const int* __restrict__ dsts,
    const float* __restrict__ Wm1, const float* __restrict__ bm1,
    const unsigned short* __restrict__ W2bf, const float* __restrict__ bm2,
    const unsigned short* __restrict__ W3bf, const float* __restrict__ bm3,
    float* __restrict__ aggr) {
  __shared__ __align__(16) char smem[39424];
  unsigned short* sH = (unsigned short*)(void*)smem;   // [0,32768): h tile bf16, swizzled
  float* sMsg = (float*)(void*)smem;                   // overlay: 4 wave slabs x 2048 fp32
  float* sAttr8 = (float*)(void*)(smem + 32768);       // 4KB: 128x8 attr rows
  float* sWm1F = (float*)(void*)(smem + 36864);        // 2.5KB: 640 floats

  const int t = threadIdx.x;
  const int wave = t >> 6, lane = t & 63;
  const int col = lane & 15, q = lane >> 4;
  const int eb = wave * 32;      // layer-1: this wave's edge rows
  const int wbase = wave * 32;   // layers 2/3: this wave's output channels
  const long blockEdge = (long)blockIdx.x * 128;

  // ---- stage: Wm1 + this block's dst-sorted attr slab (fully coalesced) ----
  for (int i = t; i < 640; i += 256) {
    sWm1F[i] = Wm1[i];
    float v = attrS[blockEdge * 5 + i];
    int e = i / 5, j = i - e * 5;
    sAttr8[e * 8 + j] = v;
  }
  // window w = lane>>4 covers edges [32w,32w+32); lane holds 2 of its dsts
  const int dE0 = dsts[blockEdge + q * 32 + col];
  const int dE1 = dsts[blockEdge + q * 32 + 16 + col];
  __syncthreads();

  // ---- layer 1 (fp32 vector): lane -> channels {lane, lane+64}, wave-own 32 rows ----
  {
    const int c = lane;
    const float* wa = sWm1F + c * 5;
    const float* wb = sWm1F + (c + 64) * 5;
    float wa0 = wa[0], wa1 = wa[1], wa2 = wa[2], wa3 = wa[3], wa4 = wa[4];
    float wb0 = wb[0], wb1 = wb[1], wb2 = wb[2], wb3 = wb[3], wb4 = wb[4];
    float ba = bm1[c], bb = bm1[c + 64];
#pragma unroll 4
    for (int e = 0; e < 32; e++) {
      const float* ar = sAttr8 + (eb + e) * 8;
      float4 a = *(const float4*)ar;
      float a4 = ar[4];
      float ha = fmaf(a.x, wa0, fmaf(a.y, wa1, fmaf(a.z, wa2, fmaf(a.w, wa3, fmaf(a4, wa4, ba)))));
      float hb = fmaf(a.x, wb0, fmaf(a.y, wb1, fmaf(a.z, wb2, fmaf(a.w, wb3, fmaf(a4, wb4, bb)))));
      sH[swz(eb + e, c)] = tobf(leaky(ha));
      sH[swz(eb + e, c + 64)] = tobf(leaky(hb));
    }
  }
  __syncthreads();  // layer-2 B-reads span all edge rows

  floatx4 acc[2][8];

  // ---- layer 2: A = W2 rows [wbase,wbase+32), prefetched; B = h from LDS ----
  {
    bf16x8 w2f[2][4];
#pragma unroll
    for (int i = 0; i < 2; i++)
#pragma unroll
      for (int ks = 0; ks < 4; ks++)
        w2f[i][ks] = *(const bf16x8*)(const void*)
            &W2bf[(wbase + i * 16 + col) * 128 + ks * 32 + q * 8];
#pragma unroll
    for (int i = 0; i < 2; i++)
#pragma unroll
      for (int j = 0; j < 8; j++) acc[i][j] = (floatx4){0.f, 0.f, 0.f, 0.f};
#pragma unroll
    for (int ks = 0; ks < 4; ks++) {
      const int kk = ks * 32 + q * 8;
#pragma unroll
      for (int et = 0; et < 8; et++) {
        bf16x8 hb = *(const bf16x8*)(const void*)&sH[swz(et * 16 + col, kk)];
        acc[0][et] = __builtin_amdgcn_mfma_f32_16x16x32_bf16(w2f[0][ks], hb, acc[0][et], 0, 0, 0);
        acc[1][et] = __builtin_amdgcn_mfma_f32_16x16x32_bf16(w2f[1][ks], hb, acc[1][et], 0, 0, 0);
      }
    }
  }
  __syncthreads();  // all waves' layer-2 reads done before h2 overwrites sH

  // ---- layer-2 epilogue: D[n][e] -> h2 back to sH (row=e, ch=n) ----
  {
    float4 b2lo = *(const float4*)&bm2[wbase + q * 4];
    float4 b2hi = *(const float4*)&bm2[wbase + 16 + q * 4];
#pragma unroll
    for (int et = 0; et < 8; et++) {
      const int e = et * 16 + col;
#pragma unroll
      for (int r = 0; r < 4; r++) {
        sH[swz(e, wbase + q * 4 + r)] = tobf(leaky(acc[0][et][r] + ((const float*)&b2lo)[r]));
        sH[swz(e, wbase + 16 + q * 4 + r)] = tobf(leaky(acc[1][et][r] + ((const float*)&b2hi)[r]));
      }
    }
  }
  __syncthreads();  // h2 complete before layer-3 reads

  // ---- layer 3: A = W3 rows, prefetched; B = h2 from LDS ----
  {
    bf16x8 w3f[2][4];
#pragma unroll
    for (int i = 0; i < 2; i++)
#pragma unroll
      for (int ks = 0; ks < 4; ks++)
        w3f[i][ks] = *(const bf16x8*)(const void*)
            &W3bf[(wbase + i * 16 + col) * 128 + ks * 32 + q * 8];
#pragma unroll
    for (int i = 0; i < 2; i++)
#pragma unroll
      for (int j = 0; j < 8; j++) acc[i][j] = (floatx4){0.f, 0.f, 0.f, 0.f};
#pragma unroll
    for (int ks = 0; ks < 4; ks++) {
      const int kk = ks * 32 + q * 8;
#pragma unroll
      for (int et = 0; et < 8; et++) {
        bf16x8 hb = *(const bf16x8*)(const void*)&sH[swz(et * 16 + col, kk)];
        acc[0][et] = __builtin_amdgcn_mfma_f32_16x16x32_bf16(w3f[0][ks], hb, acc[0][et], 0, 0, 0);
        acc[1][et] = __builtin_amdgcn_mfma_f32_16x16x32_bf16(w3f[1][ks], hb, acc[1][et], 0, 0, 0);
      }
    }
  }
  __syncthreads();  // all sH reads done; smem becomes per-wave sMsg slabs

  // ---- two 16-channel chunks: msg fp32 -> wave-private slab, then segment walk ----
  const int wslab = wave * 2048;
#pragma unroll
  for (int c = 0; c < 2; c++) {
    float4 b3 = *(const float4*)&bm3[wbase + c * 16 + q * 4];
#pragma unroll
    for (int et = 0; et < 8; et++) {
      const int e = et * 16 + col;
#pragma unroll
      for (int r = 0; r < 4; r++)
        sMsg[wslab + msw(e, q * 4 + r)] = acc[c][et][r] + ((const float*)&b3)[r];
    }
    asm volatile("s_waitcnt lgkmcnt(0)" ::: "memory");  // wave-local slab visible

    // lane -> (ch = lane&15, window = lane>>4 of 32 edges)
    const int ch = col;
    const int chG = wbase + c * 16 + ch;
    float accv = 0.f;
    int dprev = __shfl(dE0, lane & 48);
#pragma unroll 8
    for (int it = 0; it < 32; it++) {
      int d = __shfl((it < 16) ? dE0 : dE1, (lane & 48) + (it & 15));
      float v = sMsg[wslab + msw(q * 32 + it, ch)];
      if (d != dprev) {
        atomicAdd(&aggr[(size_t)dprev * 128 + chG], accv);
        accv = 0.f;
        dprev = d;
      }
      accv += v;
    }
    atomicAdd(&aggr[(size_t)dprev * 128 + chG], accv);
  }
}

// ---------------- node layer (MFMA) ----------------
template <int NT, int KST, bool FINAL>
__device__ __forceinline__ void layer_node(unsigned short* __restrict__ sX,
                                           const unsigned short* __restrict__ W,
                                           const float* __restrict__ bias, int biasLim,
                                           int wave, int lane, int nodeGBase,
                                           float* __restrict__ out) {
  const int col = lane & 15, q = lane >> 4;
  floatx4 acc[NT];
#pragma unroll
  for (int i = 0; i < NT; i++) acc[i] = (floatx4){0.f, 0.f, 0.f, 0.f};
  const int rowA = wave * 16 + col;
#pragma unroll
  for (int ks = 0; ks < KST; ks++) {
    const int kk = ks * 32 + q * 8;
    bf16x8 a = *(const bf16x8*)(const void*)&sX[rowA * STRN + kk];
#pragma unroll
    for (int nt = 0; nt < NT; nt++) {
      bf16x8 b = *(const bf16x8*)(const void*)&W[(nt * 16 + col) * (KST * 32) + kk];
      acc[nt] = __builtin_amdgcn_mfma_f32_16x16x32_bf16(a, b, acc[nt], 0, 0, 0);
    }
  }
#pragma unroll
  for (int nt = 0; nt < NT; nt++) {
    const int n = nt * 16 + col;
    const float bv = (n < biasLim) ? bias[n] : 0.f;
#pragma unroll
    for (int r = 0; r < 4; r++) {
      const int row = wave * 16 + q * 4 + r;
      float v = acc[nt][r] + bv;
      if (!FINAL) {
        sX[row * STRN + n] = tobf(leaky(v));
      } else {
        const long ng = (long)nodeGBase + row;
        if (ng < N_NODES) out[ng * 128 + n] = v;
      }
    }
  }
}

// ---------------- node kernel: LN(concat) + MLP ----------------
__global__ __launch_bounds__(256, 2) void node_kernel(
    const float* __restrict__ x, const float* __restrict__ aggr,
    const float* __restrict__ lng, const float* __restrict__ lnb,
    const unsigned short* __restrict__ Wu1p, const float* __restrict__ bu1,
    const unsigned short* __restrict__ Wu2p, const float* __restrict__ bu2,
    const unsigned short* __restrict__ Wu3p, const float* __restrict__ bu3,
    float* __restrict__ out) {
  __shared__ unsigned short sX[64 * STRN];  // [node][c] bf16, padded stride
  __shared__ float sG[256], sB[256];
  const int t = threadIdx.x;
  const int wave = t >> 6, lane = t & 63;
  sG[t] = lng[t];
  sB[t] = lnb[t];

  // LayerNorm over cat=[x,aggr] (fp32). 4 threads per node.
  const int nl = t >> 2;
  const int part = t & 3;
  const long nodeG = (long)blockIdx.x * 64 + nl;
  const bool valid = nodeG < N_NODES;
  const float* src = (part < 2) ? (x + nodeG * 128 + part * 64)
                                : (aggr + nodeG * 128 + (part - 2) * 64);
  float s = 0.f, ss = 0.f;
  if (valid) {
#pragma unroll
    for (int i = 0; i < 16; i++) {
      float4 a = *(const float4*)(src + i * 4);
      s += a.x + a.y + a.z + a.w;
      ss += a.x * a.x + a.y * a.y + a.z * a.z + a.w * a.w;
    }
  }
  s += __shfl_xor(s, 1); s += __shfl_xor(s, 2);
  ss += __shfl_xor(ss, 1); ss += __shfl_xor(ss, 2);
  const float mean = s * (1.f / 256.f);
  const float var = ss * (1.f / 256.f) - mean * mean;
  const float rstd = rsqrtf(var + 1e-5f);
  __syncthreads();  // sG/sB visible
  const int cb = part * 64;
#pragma unroll
  for (int i = 0; i < 16; i++) {
    float4 a = valid ? *(const float4*)(src + i * 4) : make_float4(0.f, 0.f, 0.f, 0.f);
    int c = cb + i * 4;
    ushort4v p;
    p[0] = tobf((a.x - mean) * rstd * sG[c + 0] + sB[c + 0]);
    p[1] = tobf((a.y - mean) * rstd * sG[c + 1] + sB[c + 1]);
    p[2] = tobf((a.z - mean) * rstd * sG[c + 2] + sB[c + 2]);
    p[3] = tobf((a.w - mean) * rstd * sG[c + 3] + sB[c + 3]);
    *(ushort4v*)(void*)&sX[nl * STRN + c] = p;
  }
  __syncthreads();

  const int nodeGBase = blockIdx.x * 64;
  layer_node<14, 8, false>(sX, Wu1p, bu1, 214, wave, lane, nodeGBase, nullptr);
  __syncthreads();
  layer_node<12, 7, false>(sX, Wu2p, bu2, 172, wave, lane, nodeGBase, nullptr);
  __syncthreads();
  layer_node<8, 6, true>(sX, Wu3p, bu3, 128, wave, lane, nodeGBase, out);
}

// ---------------- launch ----------------
extern "C" void kernel_launch(void* const* d_in, const int* in_sizes, int n_in,
                              void* d_out, int out_size, void* d_ws, size_t ws_size,
                              hipStream_t stream) {
  const float* x    = (const float*)d_in[0];
  const int*   eidx = (const int*)d_in[1];
  const float* attr = (const float*)d_in[2];
  const float* Wm1  = (const float*)d_in[3];
  const float* bm1  = (const float*)d_in[4];
  const float* Wm2  = (const float*)d_in[5];
  const float* bm2  = (const float*)d_in[6];
  const float* Wm3  = (const float*)d_in[7];
  const float* bm3  = (const float*)d_in[8];
  const float* lng  = (const float*)d_in[9];
  const float* lnb  = (const float*)d_in[10];
  const float* Wu1  = (const float*)d_in[11];
  const float* bu1  = (const float*)d_in[12];
  const float* Wu2  = (const float*)d_in[13];
  const float* bu2  = (const float*)d_in[14];
  const float* Wu3  = (const float*)d_in[15];
  const float* bu3  = (const float*)d_in[16];
  float* out = (float*)d_out;

  char* ws = (char*)d_ws;
  float* aggr  = (float*)(ws + WS_AGGR);
  int* counts  = (int*)(ws + WS_COUNTS);
  int* offs    = (int*)(ws + WS_OFFS);
  int* parts   = (int*)(ws + WS_PART);
  int* dsts    = (int*)(ws + WS_DSTS);
  float* attrS = (float*)(ws + WS_ATTRS);
  unsigned short* W2bf = (unsigned short*)(ws + WS_W2);
  unsigned short* W3bf = (unsigned short*)(ws + WS_W3);
  unsigned short* Wu1p = (unsigned short*)(ws + WS_WU1);
  unsigned short* Wu2p = (unsigned short*)(ws + WS_WU2);
  unsigned short* Wu3p = (unsigned short*)(ws + WS_WU3);

  const int* dst = eidx + N_EDGES;  // edge_index[1]

  // counting sort of edges by dst (payload reorder: attrS + dsts)
  hipMemsetAsync(counts, 0, 400384, stream);
  hist_kernel<<<6250, 256, 0, stream>>>(dst, counts);
  scanA_kernel<<<NBLK_SCAN, 256, 0, stream>>>(counts, offs, parts);
  scanB_kernel<<<1, 512, 0, stream>>>(parts);
  scanC_kernel<<<NBLK_SCAN, 256, 0, stream>>>(offs, parts);
  scatter_kernel<<<6250, 256, 0, stream>>>(dst, offs, attr, attrS, dsts);

  hipMemsetAsync(aggr, 0, (size_t)N_NODES * 128 * sizeof(float), stream);
  prep_kernel<<<616, 256, 0, stream>>>(Wm2, Wm3, Wu1, Wu2, Wu3, W2bf, W3bf, Wu1p, Wu2p, Wu3p);

  edge_kernel<<<N_EDGES / 128, 256, 0, stream>>>(attrS, dsts, Wm1, bm1, W2bf, bm2, W3bf,
                                                 bm3, aggr);
  node_kernel<<<(N_NODES + 63) / 64, 256, 0, stream>>>(x, aggr, lng, lnb, Wu1p, bu1, Wu2p, bu2,
                                                       Wu3p, bu3, out);
}

// Round 4
// 697.332 us; speedup vs baseline: 1.4226x; 1.1705x over previous
//
#include <hip/hip_runtime.h>

#define N_NODES 100000
#define N_EDGES 1600000
#define STRN 264        // node LDS row stride in ushorts (256 + 8 pad)
#define NBLK_SCAN 391   // ceil(100000/256)

typedef __attribute__((ext_vector_type(4))) float floatx4;
typedef __attribute__((ext_vector_type(8))) __bf16 bf16x8;
typedef __attribute__((ext_vector_type(8))) unsigned short ushort8;
typedef __attribute__((ext_vector_type(4))) unsigned short ushort4v;

// ---- ws layout (bytes) ----
#define WS_AGGR   0ull                        // 51,200,000  fp32 [N][128]
#define WS_COUNTS 51200000ull                 // 400,384     int[100096]
#define WS_OFFS   51600384ull                 // 400,384
#define WS_PART   52000768ull                 // 2,048       int[512]
#define WS_DSTS   52002816ull                 // 6,400,000   int[E] (dst-sorted)
#define WS_ATTRS  58402816ull                 // 32,000,000  fp32 [E][5] (dst-sorted)
#define WS_W2     90402816ull                 // Wm2 bf16 [128][128]
#define WS_W3     (WS_W2 + 32768ull)
#define WS_WU1    (WS_W3 + 32768ull)          // Wu1 bf16 padded [224][256]
#define WS_WU2    (WS_WU1 + 114688ull)        // Wu2 bf16 padded [192][224]
#define WS_WU3    (WS_WU2 + 86016ull)         // Wu3 bf16 padded [128][192]

__device__ __forceinline__ unsigned short tobf(float f) {
  return __builtin_bit_cast(unsigned short, (__bf16)f);
}

__device__ __forceinline__ float leaky(float v) { return fmaxf(v, 0.01f * v); }

// XOR-swizzled ushort index into a [128 rows][128 ch] bf16 LDS tile.
__device__ __forceinline__ int swz(int row, int ch) {
  return row * 128 + (ch ^ ((row & 7) << 3));
}

// fp32 msg slab index: [128 edges][16 ch].
__device__ __forceinline__ int msw(int e, int ch) {
  return e * 16 + (ch ^ (((e >> 1) & 3) << 2));
}

// ---------------- weight prep: fp32 -> bf16 (+ zero padding) ----------------
__global__ void prep_kernel(const float* __restrict__ Wm2, const float* __restrict__ Wm3,
                            const float* __restrict__ Wu1, const float* __restrict__ Wu2,
                            const float* __restrict__ Wu3,
                            unsigned short* __restrict__ o2, unsigned short* __restrict__ o3,
                            unsigned short* __restrict__ o1p, unsigned short* __restrict__ o2p,
                            unsigned short* __restrict__ o3p) {
  int i = blockIdx.x * 256 + threadIdx.x;
  if (i < 16384) {
    o2[i] = tobf(Wm2[i]);
  } else if (i < 32768) {
    int j = i - 16384; o3[j] = tobf(Wm3[j]);
  } else if (i < 32768 + 57344) {            // Wu1 pad [214][256] -> [224][256]
    int j = i - 32768; int n = j >> 8, k = j & 255;
    o1p[j] = (n < 214) ? tobf(Wu1[n * 256 + k]) : (unsigned short)0;
  } else if (i < 90112 + 43008) {            // Wu2 pad [172][214] -> [192][224]
    int j = i - 90112; int n = j / 224, k = j - n * 224;
    o2p[j] = (n < 172 && k < 214) ? tobf(Wu2[n * 214 + k]) : (unsigned short)0;
  } else if (i < 133120 + 24576) {           // Wu3 pad [128][172] -> [128][192]
    int j = i - 133120; int n = j / 192, k = j - n * 192;
    o3p[j] = (k < 172) ? tobf(Wu3[n * 172 + k]) : (unsigned short)0;
  }
}

// ---------------- counting sort of edges by dst ----------------
__global__ void hist_kernel(const int* __restrict__ dst, int* __restrict__ counts) {
  int e = blockIdx.x * 256 + threadIdx.x;
  if (e < N_EDGES) atomicAdd(&counts[dst[e]], 1);
}

__global__ void scanA_kernel(const int* __restrict__ counts, int* __restrict__ offs,
                             int* __restrict__ partials) {
  __shared__ int tmp[256];
  const int t = threadIdx.x;
  const int i = blockIdx.x * 256 + t;
  int v = (i < N_NODES) ? counts[i] : 0;
  tmp[t] = v;
  __syncthreads();
  for (int off = 1; off < 256; off <<= 1) {
    int a = (t >= off) ? tmp[t - off] : 0;
    __syncthreads();
    tmp[t] += a;
    __syncthreads();
  }
  if (i < N_NODES) offs[i] = tmp[t] - v;  // exclusive
  if (t == 255) partials[blockIdx.x] = tmp[255];
}

__global__ void scanB_kernel(int* __restrict__ partials) {
  __shared__ int tmp[512];
  const int t = threadIdx.x;
  int v = (t < NBLK_SCAN) ? partials[t] : 0;
  tmp[t] = v;
  __syncthreads();
  for (int off = 1; off < 512; off <<= 1) {
    int a = (t >= off) ? tmp[t - off] : 0;
    __syncthreads();
    tmp[t] += a;
    __syncthreads();
  }
  if (t < NBLK_SCAN) partials[t] = tmp[t] - v;  // exclusive
}

__global__ void scanC_kernel(int* __restrict__ offs, const int* __restrict__ partials) {
  int i = blockIdx.x * 256 + threadIdx.x;
  if (i < N_NODES) offs[i] += partials[blockIdx.x];
}

// scatter: reorder the edge PAYLOAD (attr rows + dst) into dst-sorted order.
__global__ void scatter_kernel(const int* __restrict__ dst, int* __restrict__ offs,
                               const float* __restrict__ attr,
                               float* __restrict__ attrS, int* __restrict__ dsts) {
  int e = blockIdx.x * 256 + threadIdx.x;
  if (e < N_EDGES) {
    int d = dst[e];
    int p = atomicAdd(&offs[d], 1);
    dsts[p] = d;
    const float* a = attr + (size_t)e * 5;
    float a0 = a[0], a1 = a[1], a2 = a[2], a3 = a[3], a4 = a[4];
    float* o = attrS + (size_t)p * 5;
    o[0] = a0; o[1] = a1; o[2] = a2; o[3] = a3; o[4] = a4;
  }
}

// ---------------- edge kernel (round-2 verbatim: verified passing) ----------------
// Swapped-operand MFMA: A = weight rows (wave owns 32 output channels, 8 frags
// prefetched into 32 VGPRs -> no latency chain), B = h tile from swizzled LDS.
// LDS 39.4KB -> 4 blocks/CU. Segment walk per wave over its 32 channels from a
// wave-private fp32 slab.
__global__ __launch_bounds__(256, 4) void edge_kernel(
    const float* __restrict__ attrS, const int* __restrict__ dsts,
    const float* __restrict__ Wm1, const float* __restrict__ bm1,
    const unsigned short* __restrict__ W2bf, const float* __restrict__ bm2,
    const unsigned short* __restrict__ W3bf, const float* __restrict__ bm3,
    float* __restrict__ aggr) {
  __shared__ __align__(16) char smem[39424];
  unsigned short* sH = (unsigned short*)(void*)smem;   // [0,32768): h tile bf16, swizzled
  float* sMsg = (float*)(void*)smem;                   // overlay: 4 wave slabs x 2048 fp32
  float* sAttr8 = (float*)(void*)(smem + 32768);       // 4KB: 128x8 attr rows
  float* sWm1F = (float*)(void*)(smem + 36864);        // 2.5KB: 640 floats

  const int t = threadIdx.x;
  const int wave = t >> 6, lane = t & 63;
  const int col = lane & 15, q = lane >> 4;
  const int eb = wave * 32;      // layer-1: this wave's edge rows
  const int wbase = wave * 32;   // layers 2/3: this wave's output channels
  const long blockEdge = (long)blockIdx.x * 128;

  // ---- stage: Wm1 + this block's dst-sorted attr slab (fully coalesced) ----
  for (int i = t; i < 640; i += 256) {
    sWm1F[i] = Wm1[i];
    float v = attrS[blockEdge * 5 + i];
    int e = i / 5, j = i - e * 5;
    sAttr8[e * 8 + j] = v;
  }
  // window w = lane>>4 covers edges [32w,32w+32); lane holds 2 of its dsts
  const int dE0 = dsts[blockEdge + q * 32 + col];
  const int dE1 = dsts[blockEdge + q * 32 + 16 + col];
  __syncthreads();

  // ---- layer 1 (fp32 vector): lane -> channels {lane, lane+64}, wave-own 32 rows ----
  {
    const int c = lane;
    const float* wa = sWm1F + c * 5;
    const float* wb = sWm1F + (c + 64) * 5;
    float wa0 = wa[0], wa1 = wa[1], wa2 = wa[2], wa3 = wa[3], wa4 = wa[4];
    float wb0 = wb[0], wb1 = wb[1], wb2 = wb[2], wb3 = wb[3], wb4 = wb[4];
    float ba = bm1[c], bb = bm1[c + 64];
#pragma unroll 4
    for (int e = 0; e < 32; e++) {
      const float* ar = sAttr8 + (eb + e) * 8;
      float4 a = *(const float4*)ar;
      float a4 = ar[4];
      float ha = fmaf(a.x, wa0, fmaf(a.y, wa1, fmaf(a.z, wa2, fmaf(a.w, wa3, fmaf(a4, wa4, ba)))));
      float hb = fmaf(a.x, wb0, fmaf(a.y, wb1, fmaf(a.z, wb2, fmaf(a.w, wb3, fmaf(a4, wb4, bb)))));
      sH[swz(eb + e, c)] = tobf(leaky(ha));
      sH[swz(eb + e, c + 64)] = tobf(leaky(hb));
    }
  }
  __syncthreads();  // layer-2 B-reads span all edge rows

  floatx4 acc[2][8];

  // ---- layer 2: A = W2 rows [wbase,wbase+32), prefetched; B = h from LDS ----
  {
    bf16x8 w2f[2][4];
#pragma unroll
    for (int i = 0; i < 2; i++)
#pragma unroll
      for (int ks = 0; ks < 4; ks++)
        w2f[i][ks] = *(const bf16x8*)(const void*)
            &W2bf[(wbase + i * 16 + col) * 128 + ks * 32 + q * 8];
#pragma unroll
    for (int i = 0; i < 2; i++)
#pragma unroll
      for (int j = 0; j < 8; j++) acc[i][j] = (floatx4){0.f, 0.f, 0.f, 0.f};
#pragma unroll
    for (int ks = 0; ks < 4; ks++) {
      const int kk = ks * 32 + q * 8;
#pragma unroll
      for (int et = 0; et < 8; et++) {
        bf16x8 hb = *(const bf16x8*)(const void*)&sH[swz(et * 16 + col, kk)];
        acc[0][et] = __builtin_amdgcn_mfma_f32_16x16x32_bf16(w2f[0][ks], hb, acc[0][et], 0, 0, 0);
        acc[1][et] = __builtin_amdgcn_mfma_f32_16x16x32_bf16(w2f[1][ks], hb, acc[1][et], 0, 0, 0);
      }
    }
  }
  __syncthreads();  // all waves' layer-2 reads done before h2 overwrites sH

  // ---- layer-2 epilogue: D[n][e] -> h2 back to sH (row=e, ch=n) ----
  {
    float4 b2lo = *(const float4*)&bm2[wbase + q * 4];
    float4 b2hi = *(const float4*)&bm2[wbase + 16 + q * 4];
#pragma unroll
    for (int et = 0; et < 8; et++) {
      const int e = et * 16 + col;
#pragma unroll
      for (int r = 0; r < 4; r++) {
        sH[swz(e, wbase + q * 4 + r)] = tobf(leaky(acc[0][et][r] + ((const float*)&b2lo)[r]));
        sH[swz(e, wbase + 16 + q * 4 + r)] = tobf(leaky(acc[1][et][r] + ((const float*)&b2hi)[r]));
      }
    }
  }
  __syncthreads();  // h2 complete before layer-3 reads

  // ---- layer 3: A = W3 rows, prefetched; B = h2 from LDS ----
  {
    bf16x8 w3f[2][4];
#pragma unroll
    for (int i = 0; i < 2; i++)
#pragma unroll
      for (int ks = 0; ks < 4; ks++)
        w3f[i][ks] = *(const bf16x8*)(const void*)
            &W3bf[(wbase + i * 16 + col) * 128 + ks * 32 + q * 8];
#pragma unroll
    for (int i = 0; i < 2; i++)
#pragma unroll
      for (int j = 0; j < 8; j++) acc[i][j] = (floatx4){0.f, 0.f, 0.f, 0.f};
#pragma unroll
    for (int ks = 0; ks < 4; ks++) {
      const int kk = ks * 32 + q * 8;
#pragma unroll
      for (int et = 0; et < 8; et++) {
        bf16x8 hb = *(const bf16x8*)(const void*)&sH[swz(et * 16 + col, kk)];
        acc[0][et] = __builtin_amdgcn_mfma_f32_16x16x32_bf16(w3f[0][ks], hb, acc[0][et], 0, 0, 0);
        acc[1][et] = __builtin_amdgcn_mfma_f32_16x16x32_bf16(w3f[1][ks], hb, acc[1][et], 0, 0, 0);
      }
    }
  }
  __syncthreads();  // all sH reads done; smem becomes per-wave sMsg slabs

  // ---- two 16-channel chunks: msg fp32 -> wave-private slab, then segment walk ----
  const int wslab = wave * 2048;
#pragma unroll
  for (int c = 0; c < 2; c++) {
    float4 b3 = *(const float4*)&bm3[wbase + c * 16 + q * 4];
#pragma unroll
    for (int et = 0; et < 8; et++) {
      const int e = et * 16 + col;
#pragma unroll
      for (int r = 0; r < 4; r++)
        sMsg[wslab + msw(e, q * 4 + r)] = acc[c][et][r] + ((const float*)&b3)[r];
    }
    asm volatile("s_waitcnt lgkmcnt(0)" ::: "memory");  // wave-local slab visible

    // lane -> (ch = lane&15, window = q of 32 edges)
    const int ch = col;
    const int chG = wbase + c * 16 + ch;
    float accv = 0.f;
    int dprev = __shfl(dE0, lane & 48);
#pragma unroll 8
    for (int it = 0; it < 32; it++) {
      int d = __shfl((it < 16) ? dE0 : dE1, (lane & 48) + (it & 15));
      float v = sMsg[wslab + msw(q * 32 + it, ch)];
      if (d != dprev) {
        atomicAdd(&aggr[(size_t)dprev * 128 + chG], accv);
        accv = 0.f;
        dprev = d;
      }
      accv += v;
    }
    atomicAdd(&aggr[(size_t)dprev * 128 + chG], accv);
  }
}

// ---------------- node layer (swapped-operand MFMA) ----------------
// Wave owns chan tiles {wave + 4j}; A = W rows prefetched per-ks (reused over
// 4 node tiles), B = nodes from LDS. a[c] always loaded in-bounds (no undef
// operand ever reaches an intrinsic); MFMA + epilogue guarded by tile<TILES.
template <int TILES, int CT, int KST, bool FINAL>
__device__ __forceinline__ void layer_node_sw(unsigned short* __restrict__ sX,
                                              const unsigned short* __restrict__ W,
                                              const float* __restrict__ bias, int biasLim,
                                              int wave, int lane, int nodeGBase,
                                              float* __restrict__ out) {
  const int col = lane & 15, q = lane >> 4;
  const int K = KST * 32;
  floatx4 acc[CT][4];
#pragma unroll
  for (int c = 0; c < CT; c++)
#pragma unroll
    for (int n = 0; n < 4; n++) acc[c][n] = (floatx4){0.f, 0.f, 0.f, 0.f};

#pragma unroll
  for (int ks = 0; ks < KST; ks++) {
    const int kk = ks * 32 + q * 8;
    bf16x8 a[CT];
#pragma unroll
    for (int c = 0; c < CT; c++) {
      const int tile = wave + 4 * c;
      const int tc = (tile < TILES) ? tile : 0;  // always defined, always in-bounds
      a[c] = *(const bf16x8*)(const void*)&W[(tc * 16 + col) * K + kk];
    }
    bf16x8 b[4];
#pragma unroll
    for (int n = 0; n < 4; n++)
      b[n] = *(const bf16x8*)(const void*)&sX[(n * 16 + col) * STRN + kk];
#pragma unroll
    for (int c = 0; c < CT; c++) {
      if (wave + 4 * c < TILES) {
#pragma unroll
        for (int n = 0; n < 4; n++)
          acc[c][n] = __builtin_amdgcn_mfma_f32_16x16x32_bf16(a[c], b[n], acc[c][n], 0, 0, 0);
      }
    }
  }
  __syncthreads();  // all waves done reading sX before epilogue overwrites

#pragma unroll
  for (int c = 0; c < CT; c++) {
    const int tile = wave + 4 * c;
    if (tile < TILES) {
      float bv[4];
#pragma unroll
      for (int r = 0; r < 4; r++) {
        const int ch = tile * 16 + q * 4 + r;
        bv[r] = (ch < biasLim) ? bias[ch] : 0.f;
      }
#pragma unroll
      for (int n = 0; n < 4; n++) {
        const int node = n * 16 + col;
        if (!FINAL) {
          ushort4v p;
#pragma unroll
          for (int r = 0; r < 4; r++) p[r] = tobf(leaky(acc[c][n][r] + bv[r]));
          *(ushort4v*)(void*)&sX[node * STRN + tile * 16 + q * 4] = p;
        } else {
          const long ng = (long)nodeGBase + node;
          if (ng < N_NODES) {
            float4 p = make_float4(acc[c][n][0] + bv[0], acc[c][n][1] + bv[1],
                                   acc[c][n][2] + bv[2], acc[c][n][3] + bv[3]);
            *(float4*)(void*)&out[ng * 128 + tile * 16 + q * 4] = p;
          }
        }
      }
    }
  }
  if (!FINAL) __syncthreads();  // writes visible before next layer reads
}

// ---------------- node kernel: LN(concat) + MLP ----------------
__global__ __launch_bounds__(256, 4) void node_kernel(
    const float* __restrict__ x, const float* __restrict__ aggr,
    const float* __restrict__ lng, const float* __restrict__ lnb,
    const unsigned short* __restrict__ Wu1p, const float* __restrict__ bu1,
    const unsigned short* __restrict__ Wu2p, const float* __restrict__ bu2,
    const unsigned short* __restrict__ Wu3p, const float* __restrict__ bu3,
    float* __restrict__ out) {
  __shared__ unsigned short sX[64 * STRN];  // [node][c] bf16, padded stride
  __shared__ float sG[256], sB[256];
  const int t = threadIdx.x;
  const int wave = t >> 6, lane = t & 63;
  sG[t] = lng[t];
  sB[t] = lnb[t];

  // LayerNorm over cat=[x,aggr] (fp32). 4 threads per node.
  const int nl = t >> 2;
  const int part = t & 3;
  const long nodeG = (long)blockIdx.x * 64 + nl;
  const bool valid = nodeG < N_NODES;
  const float* src = (part < 2) ? (x + nodeG * 128 + part * 64)
                                : (aggr + nodeG * 128 + (part - 2) * 64);
  float s = 0.f, ss = 0.f;
  if (valid) {
#pragma unroll
    for (int i = 0; i < 16; i++) {
      float4 a = *(const float4*)(src + i * 4);
      s += a.x + a.y + a.z + a.w;
      ss += a.x * a.x + a.y * a.y + a.z * a.z + a.w * a.w;
    }
  }
  s += __shfl_xor(s, 1); s += __shfl_xor(s, 2);
  ss += __shfl_xor(ss, 1); ss += __shfl_xor(ss, 2);
  const float mean = s * (1.f / 256.f);
  const float var = ss * (1.f / 256.f) - mean * mean;
  const float rstd = rsqrtf(var + 1e-5f);
  __syncthreads();  // sG/sB visible
  const int cb = part * 64;
#pragma unroll
  for (int i = 0; i < 16; i++) {
    float4 a = valid ? *(const float4*)(src + i * 4) : make_float4(0.f, 0.f, 0.f, 0.f);
    int c = cb + i * 4;
    ushort4v p;
    p[0] = tobf((a.x - mean) * rstd * sG[c + 0] + sB[c + 0]);
    p[1] = tobf((a.y - mean) * rstd * sG[c + 1] + sB[c + 1]);
    p[2] = tobf((a.z - mean) * rstd * sG[c + 2] + sB[c + 2]);
    p[3] = tobf((a.w - mean) * rstd * sG[c + 3] + sB[c + 3]);
    *(ushort4v*)(void*)&sX[nl * STRN + c] = p;
  }
  __syncthreads();

  const int nodeGBase = blockIdx.x * 64;
  layer_node_sw<14, 4, 8, false>(sX, Wu1p, bu1, 214, wave, lane, nodeGBase, nullptr);
  layer_node_sw<12, 3, 7, false>(sX, Wu2p, bu2, 172, wave, lane, nodeGBase, nullptr);
  layer_node_sw<8, 2, 6, true>(sX, Wu3p, bu3, 128, wave, lane, nodeGBase, out);
}

// ---------------- launch ----------------
extern "C" void kernel_launch(void* const* d_in, const int* in_sizes, int n_in,
                              void* d_out, int out_size, void* d_ws, size_t ws_size,
                              hipStream_t stream) {
  const float* x    = (const float*)d_in[0];
  const int*   eidx = (const int*)d_in[1];
  const float* attr = (const float*)d_in[2];
  const float* Wm1  = (const float*)d_in[3];
  const float* bm1  = (const float*)d_in[4];
  const float* Wm2  = (const float*)d_in[5];
  const float* bm2  = (const float*)d_in[6];
  const float* Wm3  = (const float*)d_in[7];
  const float* bm3  = (const float*)d_in[8];
  const float* lng  = (const float*)d_in[9];
  const float* lnb  = (const float*)d_in[10];
  const float* Wu1  = (const float*)d_in[11];
  const float* bu1  = (const float*)d_in[12];
  const float* Wu2  = (const float*)d_in[13];
  const float* bu2  = (const float*)d_in[14];
  const float* Wu3  = (const float*)d_in[15];
  const float* bu3  = (const float*)d_in[16];
  float* out = (float*)d_out;

  char* ws = (char*)d_ws;
  float* aggr  = (float*)(ws + WS_AGGR);
  int* counts  = (int*)(ws + WS_COUNTS);
  int* offs    = (int*)(ws + WS_OFFS);
  int* parts   = (int*)(ws + WS_PART);
  int* dsts    = (int*)(ws + WS_DSTS);
  float* attrS = (float*)(ws + WS_ATTRS);
  unsigned short* W2bf = (unsigned short*)(ws + WS_W2);
  unsigned short* W3bf = (unsigned short*)(ws + WS_W3);
  unsigned short* Wu1p = (unsigned short*)(ws + WS_WU1);
  unsigned short* Wu2p = (unsigned short*)(ws + WS_WU2);
  unsigned short* Wu3p = (unsigned short*)(ws + WS_WU3);

  const int* dst = eidx + N_EDGES;  // edge_index[1]

  // counting sort of edges by dst (payload reorder: attrS + dsts)
  hipMemsetAsync(counts, 0, 400384, stream);
  hist_kernel<<<6250, 256, 0, stream>>>(dst, counts);
  scanA_kernel<<<NBLK_SCAN, 256, 0, stream>>>(counts, offs, parts);
  scanB_kernel<<<1, 512, 0, stream>>>(parts);
  scanC_kernel<<<NBLK_SCAN, 256, 0, stream>>>(offs, parts);
  scatter_kernel<<<6250, 256, 0, stream>>>(dst, offs, attr, attrS, dsts);

  hipMemsetAsync(aggr, 0, (size_t)N_NODES * 128 * sizeof(float), stream);
  prep_kernel<<<616, 256, 0, stream>>>(Wm2, Wm3, Wu1, Wu2, Wu3, W2bf, W3bf, Wu1p, Wu2p, Wu3p);

  edge_kernel<<<N_EDGES / 128, 256, 0, stream>>>(attrS, dsts, Wm1, bm1, W2bf, bm2, W3bf,
                                                 bm3, aggr);
  node_kernel<<<(N_NODES + 63) / 64, 256, 0, stream>>>(x, aggr, lng, lnb, Wu1p, bu1, Wu2p, bu2,
                                                       Wu3p, bu3, out);
}